// Round 12
// baseline (1756.733 us; speedup 1.0000x reference)
//
#include <hip/hip_runtime.h>

// Neural-ODE RK4 over MLP 12->300->100->50->12, B=1024, T=100.
// R12: 256 blocks x 1024 threads (16 waves, 4/SIMD), 4 elems/block.
// L2 k-split 16 ways -> W2 regs 38/thread -> packed FMA fits WITHOUT spill
// (R8/R9's packed win, R4's clean-register regime). W1 in regs (waves 0-4).
// pL2 stored [e][col][20] so the 16-partial reduce is 4 conflict-free b128.
// Wave-local tail on waves 12-15 (reduce+L3+L4+RK4, register state),
// 3 barriers/eval.

typedef float v2f __attribute__((ext_vector_type(2)));
typedef float v4f __attribute__((ext_vector_type(4)));

constexpr int TT = 100;
constexpr int D  = 12;
constexpr int H1 = 300;
constexpr int H2 = 100;
constexpr int H3 = 50;
constexpr float NEG = 0.01f;

__device__ __forceinline__ float lrelu(float x) { return fmaxf(x, NEG * x); }
__device__ __forceinline__ v2f lo2(v4f v) { return __builtin_shufflevector(v, v, 0, 1); }
__device__ __forceinline__ v2f hi2(v4f v) { return __builtin_shufflevector(v, v, 2, 3); }
__device__ __forceinline__ v2f pkfma(v2f a, v2f b, v2f c) {
#if __has_builtin(__builtin_elementwise_fma)
    return __builtin_elementwise_fma(a, b, c);
#else
    return a * b + c;
#endif
}

__global__ __launch_bounds__(1024)
void node_rk4_kernel(const float* __restrict__ y0, const float* __restrict__ t,
                     const float* __restrict__ W1, const float* __restrict__ b1,
                     const float* __restrict__ W2, const float* __restrict__ b2,
                     const float* __restrict__ W3, const float* __restrict__ b3,
                     const float* __restrict__ W4, const float* __restrict__ b4,
                     float* __restrict__ out)
{
    // LDS ~ 62 KB
    __shared__ __align__(16) float sW3c[25 * 200];    // [c][j][4k] chunked W3
    __shared__ __align__(16) float sW4 [52 * 12];     // [k][j], rows 50,51 zero
    __shared__ __align__(16) float h1T [304 * 4];     // [k][e], k=300..303 zero
    __shared__ __align__(16) float pL2v[4 * 100 * 20];// [e][col][w-pitch20]
    __shared__ __align__(16) float h2e [4 * 104];     // [e][104]
    __shared__ __align__(16) float h3e [4 * 52];      // [e][52], cols 50,51 zero
    __shared__ __align__(16) float sx  [48];
    __shared__ __align__(16) float sxe [48];
    __shared__ float st [100];

    const int tid = threadIdx.x;
    const int l   = tid & 63;
    const int w   = tid >> 6;            // wave 0..15 = L2 k-sixteenth
    const bool l2act = (l < 50);

    // ---- W2 in regs: wave w owns k = w*19 .. w*19+18; lane l owns cols l, l+50 ----
    float w2a[19], w2b[19];
#pragma unroll
    for (int i = 0; i < 19; ++i) {
        const int k = w * 19 + i;
        float va = 0.0f, vb = 0.0f;
        if (l2act && k < H1) { va = W2[k * H2 + l]; vb = W2[k * H2 + l + 50]; }
        w2a[i] = va; w2b[i] = vb;
    }

    // ---- W1 in regs: thread j<300 owns col j (waves 0-4, disjoint from tail) ----
    const bool l1act = (tid < H1);
    float w1v[12];
    float rb1 = 0.0f;
#pragma unroll
    for (int k = 0; k < 12; ++k) w1v[k] = 0.0f;
    if (l1act) {
        rb1 = b1[tid];
#pragma unroll
        for (int k = 0; k < 12; ++k) w1v[k] = W1[k * H1 + tid];
    }

    // ---- tail on waves 12-15: elem e = w-12 ----
    const bool tact = (w >= 12);
    const int  e_t  = w - 12;
    float rb2a = 0.f, rb2b = 0.f, rb3 = 0.f;
    if (tact && l2act) { rb2a = b2[l]; rb2b = b2[l + 50]; rb3 = b3[l]; }
    const int j4 = l >> 2, kq4 = l & 3;             // L4 mapping (lanes < 48)
    const float b4v = (tact && l < 48) ? b4[j4] : 0.0f;

    // ---- one-time LDS staging ----
    for (int i = tid; i < H2 * H3; i += 1024) {     // W3 [k=100][j=50] -> chunked
        const int k = i / H3, j = i - k * H3;
        sW3c[(k >> 2) * 200 + j * 4 + (k & 3)] = W3[i];
    }
    for (int i = tid; i < 52 * 12; i += 1024) sW4[i] = (i < H3 * D) ? W4[i] : 0.0f;
    if (tid < TT) st[tid] = t[tid];                 // t row 0 (uniform over batch)
    if (tid >= 104 && tid < 120) h1T[300 * 4 + (tid - 104)] = 0.0f;  // k pads
    if (tid >= 120 && tid < 128) {                  // h3e cols 50,51 zero
        const int u = tid - 120;
        h3e[(u >> 1) * 52 + 50 + (u & 1)] = 0.0f;
    }
    if (tid < 48) {                                 // x0 = y0[:,0,:]; out[:,0,:]
        const int e = tid / 12, j = tid - e * 12;
        const int g = (blockIdx.x * 4 + e) * (TT * D) + j;
        const float v = y0[g];
        sx[tid] = v;
        out[g]  = v;
    }
    __syncthreads();

    // RK4 state in registers of lane (kq4==0, j4) of tail wave e
    float xreg = 0.0f, ks = 0.0f;
    if (tact && l < 48 && kq4 == 0) xreg = sx[e_t * 12 + j4];

    for (int s = 0; s < TT - 1; ++s) {
        const float dt = st[s + 1] - st[s];
#pragma unroll 1
        for (int ev = 0; ev < 4; ++ev) {
            const float* xin = ev ? sxe : sx;

            // ===== L1: 12 -> 300, col = tid, W1 regs, writes h1T[j][0..3] =====
            if (l1act) {
                v4f r;
#pragma unroll
                for (int e = 0; e < 4; ++e) {
                    const v4f x0 = *(const v4f*)(xin + e * 12);
                    const v4f x1 = *(const v4f*)(xin + e * 12 + 4);
                    const v4f x2 = *(const v4f*)(xin + e * 12 + 8);
                    float a = rb1;
                    a = fmaf(x0.x, w1v[0], a);  a = fmaf(x0.y, w1v[1], a);
                    a = fmaf(x0.z, w1v[2], a);  a = fmaf(x0.w, w1v[3], a);
                    a = fmaf(x1.x, w1v[4], a);  a = fmaf(x1.y, w1v[5], a);
                    a = fmaf(x1.z, w1v[6], a);  a = fmaf(x1.w, w1v[7], a);
                    a = fmaf(x2.x, w1v[8], a);  a = fmaf(x2.y, w1v[9], a);
                    a = fmaf(x2.z, w1v[10], a); a = fmaf(x2.w, w1v[11], a);
                    r[e] = lrelu(a);
                }
                *(v4f*)(h1T + tid * 4) = r;
            }
            __syncthreads();                        // A: h1T ready

            // ===== L2: 300 -> 100, 19 k/wave, reg weights, packed =====
            {
                v2f a01A = {0,0}, a23A = {0,0}, a01B = {0,0}, a23B = {0,0};
                const float* hb = h1T + w * (19 * 4);
#pragma unroll
                for (int i = 0; i < 19; ++i) {
                    const v4f hv = *(const v4f*)(hb + i * 4);   // elems 0..3 at k
                    const v2f wA = {w2a[i], w2a[i]};
                    const v2f wB = {w2b[i], w2b[i]};
                    a01A = pkfma(lo2(hv), wA, a01A);
                    a23A = pkfma(hi2(hv), wA, a23A);
                    a01B = pkfma(lo2(hv), wB, a01B);
                    a23B = pkfma(hi2(hv), wB, a23B);
                }
                if (l2act) {
                    pL2v[(0 * 100 + l) * 20 + w]      = a01A.x;
                    pL2v[(1 * 100 + l) * 20 + w]      = a01A.y;
                    pL2v[(2 * 100 + l) * 20 + w]      = a23A.x;
                    pL2v[(3 * 100 + l) * 20 + w]      = a23A.y;
                    pL2v[(0 * 100 + l + 50) * 20 + w] = a01B.x;
                    pL2v[(1 * 100 + l + 50) * 20 + w] = a01B.y;
                    pL2v[(2 * 100 + l + 50) * 20 + w] = a23B.x;
                    pL2v[(3 * 100 + l + 50) * 20 + w] = a23B.y;
                }
            }
            __syncthreads();                        // B: pL2v ready

            // ===== wave-local tail: waves 12-15, elem e = w-12 =====
            if (tact) {
                const int e = e_t;
                if (l2act) {
                    // 16-partial reduce as 4 b128 per column (pitch 20, no conflicts)
                    const float* pa = pL2v + (e * 100 + l) * 20;
                    const float* pb = pL2v + (e * 100 + l + 50) * 20;
                    const v4f A0 = *(const v4f*)(pa + 0),  A1 = *(const v4f*)(pa + 4);
                    const v4f A2 = *(const v4f*)(pa + 8),  A3 = *(const v4f*)(pa + 12);
                    const v4f B0 = *(const v4f*)(pb + 0),  B1 = *(const v4f*)(pb + 4);
                    const v4f B2 = *(const v4f*)(pb + 8),  B3 = *(const v4f*)(pb + 12);
                    const v4f SA = (A0 + A1) + (A2 + A3);
                    const v4f SB = (B0 + B1) + (B2 + B3);
                    const float h2a = lrelu(SA.x + SA.y + SA.z + SA.w + rb2a);
                    const float h2b = lrelu(SB.x + SB.y + SB.z + SB.w + rb2b);
                    h2e[e * 104 + l]      = h2a;
                    h2e[e * 104 + l + 50] = h2b;
                    // L3 (in-wave LDS round trip; compiler emits lgkmcnt)
                    v2f acc = {0, 0};
                    const float* hb2 = h2e + e * 104;
                    const float* wb  = sW3c + l * 4;
#pragma unroll
                    for (int c = 0; c < 25; ++c) {
                        const v4f wv = *(const v4f*)(wb + c * 200);
                        const v4f hv = *(const v4f*)(hb2 + c * 4);
                        acc = pkfma(lo2(hv), lo2(wv), acc);
                        acc = pkfma(hi2(hv), hi2(wv), acc);
                    }
                    h3e[e * 52 + l] = lrelu(acc.x + acc.y + rb3);
                }
                // L4: lanes<48, (j4, kq4) split + shfl reduce, fused RK4
                if (l < 48) {
                    const int kb = kq4 * 13;
                    float a = 0.0f;
#pragma unroll
                    for (int i = 0; i < 13; ++i)    // k<=51: pads are zero
                        a = fmaf(h3e[e * 52 + kb + i], sW4[(kb + i) * 12 + j4], a);
                    a += __shfl_xor(a, 1);
                    a += __shfl_xor(a, 2);
                    if (kq4 == 0) {
                        a += b4v;
                        const int bi = e * 12 + j4;
                        if (ev == 0)      { ks = a;          sxe[bi] = xreg + 0.5f * dt * a; }
                        else if (ev == 1) { ks += 2.f * a;   sxe[bi] = xreg + 0.5f * dt * a; }
                        else if (ev == 2) { ks += 2.f * a;   sxe[bi] = xreg + dt * a; }
                        else {
                            const float xn = xreg + dt * (1.0f / 6.0f) * (ks + a);
                            xreg = xn;
                            sx[bi] = xn;
                            out[(blockIdx.x * 4 + e) * (TT * D) + (s + 1) * D + j4] = xn;
                        }
                    }
                }
            }
            __syncthreads();                        // C: state ready
        }
    }
}

extern "C" void kernel_launch(void* const* d_in, const int* in_sizes, int n_in,
                              void* d_out, int out_size, void* d_ws, size_t ws_size,
                              hipStream_t stream) {
    const float* y0 = (const float*)d_in[0];
    const float* t  = (const float*)d_in[1];
    const float* W1 = (const float*)d_in[2];
    const float* b1 = (const float*)d_in[3];
    const float* W2 = (const float*)d_in[4];
    const float* b2 = (const float*)d_in[5];
    const float* W3 = (const float*)d_in[6];
    const float* b3 = (const float*)d_in[7];
    const float* W4 = (const float*)d_in[8];
    const float* b4 = (const float*)d_in[9];
    float* out = (float*)d_out;

    node_rk4_kernel<<<256, 1024, 0, stream>>>(y0, t, W1, b1, W2, b2, W3, b3, W4, b4, out);
}